// Round 5
// baseline (292.225 us; speedup 1.0000x reference)
//
#include <hip/hip_runtime.h>
#include <hip/hip_bf16.h>

#define KDIM 1024   // 2*ENC_H
#define HDIM 1024   // DEC_H
#define BM   64
#define SPART 65536

typedef __attribute__((ext_vector_type(8))) short bf16x8_t;
typedef __attribute__((ext_vector_type(16))) float f32x16_t;
typedef __attribute__((ext_vector_type(4))) float f32x4_t;
typedef __attribute__((ext_vector_type(4))) unsigned int u32x4_t;
typedef __attribute__((ext_vector_type(2))) unsigned int u32x2_t;

__device__ __forceinline__ unsigned int pack2bf(float a, float b) {
    union { float f; unsigned int u; } ua, ub;
    ua.f = a; ub.f = b;
    unsigned int ra = (ua.u + 0x7fffu + ((ua.u >> 16) & 1u)) >> 16;  // RNE
    unsigned int rb = (ub.u + 0x7fffu + ((ub.u >> 16) & 1u)) >> 16;
    return ra | (rb << 16);
}

__device__ __forceinline__ unsigned int cvtpk(float lo, float hi) {
    unsigned int r;
    asm("v_cvt_pk_bf16_f32 %0, %1, %2" : "=v"(r) : "v"(lo), "v"(hi));
    return r;
}

// ---- kernel 1a: W_e -> bf16, fragment-order layout we_t[ks][h][16] ----
// element (h, e) -> we_t[(e>>4)*16384 + h*16 + (e&15)]
__global__ void cvt_we_k(const float* __restrict__ attn_w, unsigned short* __restrict__ we_t) {
    const int h = blockIdx.x;      // 1024
    const int t = threadIdx.x;     // 256 (handles e = 4t..4t+3)
    const f32x4_t v = *(const f32x4_t*)(attn_w + (size_t)h * 2048 + 1024 + (size_t)t * 4);
    u32x2_t o;
    o[0] = pack2bf(v[0], v[1]);
    o[1] = pack2bf(v[2], v[3]);
    const int ks  = t >> 2;         // e/16
    const int e15 = (t & 3) * 4;    // e&15
    *(u32x2_t*)&we_t[(size_t)ks * 16384 + h * 16 + e15] = o;
}

// ---- kernel 1b: proj_s[b][h] = sum_d s[b,d] * attn_w[h, d]  (fp32) ----
__global__ void proj_s_k(const float* __restrict__ s, const float* __restrict__ attn_w,
                         float* __restrict__ ps) {
    const int h = (blockIdx.x * blockDim.x + threadIdx.x) >> 6;  // 0..1023
    const int lane = threadIdx.x & 63;
    const float* wr = attn_w + (size_t)h * 2048;
    float w[16];
#pragma unroll
    for (int i = 0; i < 16; ++i) w[i] = wr[lane + 64 * i];
    for (int b = 0; b < 32; ++b) {
        const float* sr = s + (size_t)b * 1024;
        float a = 0.f;
#pragma unroll
        for (int i = 0; i < 16; ++i) a = fmaf(w[i], sr[lane + 64 * i], a);
#pragma unroll
        for (int off = 32; off >= 1; off >>= 1) a += __shfl_xor(a, off, 64);
        if (lane == 0) ps[b * 1024 + h] = a;
    }
}

// ---- kernel 2: fused pe-GEMM(32x32x16 MFMA) + tanh + v-dot -> partial scores ----
// 2048 blocks: (m_tile, hhalf=bid&1 so siblings co-resident -> L3 reuse of enc).
// Counted-wait barrier (lgkmcnt(0)+raw s_barrier): B/A prefetches stay in flight
// across kc boundaries (no vmcnt(0) drain -- the R4 structural stall).
__launch_bounds__(512, 4)
__global__ void fused_main_k(const float* __restrict__ enc,
                             const unsigned short* __restrict__ we_t,
                             const float* __restrict__ ps,
                             const float* __restrict__ vw,
                             float* __restrict__ scores_part) {
    __shared__ unsigned short lds_a[2 * 64 * 128];  // 32 KB ring

    const int t = threadIdx.x;
    const int bid = blockIdx.x;
    const int hhalf = bid & 1;
    const int rest = bid >> 1;                      // 0..1023
    const int m_swz = (rest & 7) * 128 + (rest >> 3);   // XCD-bijective
    const int m_base = m_swz * BM;
    const int bidx = m_swz >> 5;        // batch index

    const int lane = t & 63;
    const int wid  = t >> 6;        // 0..7
    const int l31  = lane & 31;
    const int h5   = lane >> 5;     // 0..1
    const int habs = hhalf * 512 + wid * 64;

    // staging geometry: thread covers rows {srow, 32+srow}, 16B chunk sc8
    const int srow = t >> 4;        // 0..31
    const int sc8  = t & 15;

    auto stage_load_half = [&](int kc, int half, f32x4_t* r) {
        const int row = half * 32 + srow;
        const float* p = enc + (size_t)(m_base + row) * KDIM + kc * 128 + sc8 * 8;
        r[0] = *(const f32x4_t*)p;
        r[1] = *(const f32x4_t*)(p + 4);
    };
    auto stage_write_half = [&](int kc, int half, const f32x4_t* r) {
        const int slot = kc & 1;
        const int row = half * 32 + srow;
        u32x4_t pk;
        pk[0] = cvtpk(r[0][0], r[0][1]);
        pk[1] = cvtpk(r[0][2], r[0][3]);
        pk[2] = cvtpk(r[1][0], r[1][1]);
        pk[3] = cvtpk(r[1][2], r[1][3]);
        *(u32x4_t*)&lds_a[slot * 8192 + row * 128 + ((sc8 ^ (row & 15)) << 3)] = pk;
    };

    // B: fragment-order; frag(g, nf) at btile + g*16384 + nf*512 (shorts)
    const unsigned short* btile = we_t + (size_t)(habs + l31) * 16 + h5 * 8;
    auto loadB = [&](int g, bf16x8_t* dst) {
        const unsigned short* bp = btile + (size_t)g * 16384;
        dst[0] = *(const bf16x8_t*)(bp);
        dst[1] = *(const bf16x8_t*)(bp + 512);
    };

    f32x16_t acc[2][2];
#pragma unroll
    for (int m = 0; m < 2; ++m)
#pragma unroll
        for (int nf = 0; nf < 2; ++nf)
#pragma unroll
            for (int r = 0; r < 16; ++r) acc[m][nf][r] = 0.f;

    bf16x8_t bbuf[4][2];
    f32x4_t rsA[2], rsB[2];

    // prologue: B prefetch g=0..2, stage kc=0 into slot 0
    loadB(0, bbuf[0]);
    loadB(1, bbuf[1]);
    loadB(2, bbuf[2]);
    stage_load_half(0, 0, rsA);
    stage_load_half(0, 1, rsB);
    stage_write_half(0, 0, rsA);
    stage_write_half(0, 1, rsB);
    __syncthreads();

#pragma unroll
    for (int g = 0; g < 64; ++g) {
        const int kc  = g >> 3;
        const int ksl = g & 7;

        if (g + 3 < 64) loadB(g + 3, bbuf[(g + 3) & 3]);          // depth-3 B prefetch
        if (ksl == 0 && kc < 7) stage_load_half(kc + 1, 0, rsA);  // ~5 g cover to write
        if (ksl == 2 && kc < 7) stage_load_half(kc + 1, 1, rsB);

        const unsigned short* slotp = lds_a + (kc & 1) * 8192;
        const int ch = (((ksl << 1) + h5) ^ (l31 & 15)) << 3;     // 4-bit row-XOR swizzle
        const bf16x8_t a0 = *(const bf16x8_t*)&slotp[l31 * 128 + ch];
        const bf16x8_t a1 = *(const bf16x8_t*)&slotp[(32 + l31) * 128 + ch];
        const bf16x8_t* bfr = bbuf[g & 3];
        __builtin_amdgcn_s_setprio(1);
        acc[0][0] = __builtin_amdgcn_mfma_f32_32x32x16_bf16(a0, bfr[0], acc[0][0], 0, 0, 0);
        acc[1][0] = __builtin_amdgcn_mfma_f32_32x32x16_bf16(a1, bfr[0], acc[1][0], 0, 0, 0);
        acc[0][1] = __builtin_amdgcn_mfma_f32_32x32x16_bf16(a0, bfr[1], acc[0][1], 0, 0, 0);
        acc[1][1] = __builtin_amdgcn_mfma_f32_32x32x16_bf16(a1, bfr[1], acc[1][1], 0, 0, 0);
        __builtin_amdgcn_s_setprio(0);

        if (ksl == 5 && kc < 7) stage_write_half(kc + 1, 0, rsA);
        if (ksl == 7) {
            if (kc < 7) stage_write_half(kc + 1, 1, rsB);
            // counted-wait barrier: order LDS, keep global prefetches in flight
            asm volatile("s_waitcnt lgkmcnt(0)" ::: "memory");
            __builtin_amdgcn_sched_barrier(0);
            __builtin_amdgcn_s_barrier();
            __builtin_amdgcn_sched_barrier(0);
        }
    }

    // ---- epilogue: tanh(ps + pe) * v, per-lane partials over C-rows ----
    float sc2[2][16];
#pragma unroll
    for (int m = 0; m < 2; ++m)
#pragma unroll
        for (int r = 0; r < 16; ++r) sc2[m][r] = 0.f;

#pragma unroll
    for (int nf = 0; nf < 2; ++nf) {
        const int h = habs + nf * 32 + l31;
        const float pv = ps[bidx * 1024 + h];
        const float vv = vw[h];
#pragma unroll
        for (int m = 0; m < 2; ++m)
#pragma unroll
            for (int r = 0; r < 16; ++r) {
                const float x = acc[m][nf][r] + pv;
                const float e = __expf(2.0f * x);
                const float th = 1.0f - __fdividef(2.0f, e + 1.0f);
                sc2[m][r] = fmaf(vv, th, sc2[m][r]);
            }
    }

    // reduce over the 32-lane column group (h dimension); h5 preserved
#pragma unroll
    for (int off = 1; off < 32; off <<= 1)
#pragma unroll
        for (int m = 0; m < 2; ++m)
#pragma unroll
            for (int r = 0; r < 16; ++r)
                sc2[m][r] += __shfl_xor(sc2[m][r], off, 64);

    __syncthreads();   // loop done; safe to reuse LDS front as partials buffer
    float* slds = (float*)lds_a;   // [8 waves][64 rows]
    if (l31 == 0) {
#pragma unroll
        for (int m = 0; m < 2; ++m)
#pragma unroll
            for (int r = 0; r < 16; ++r) {
                const int row = m * 32 + (r & 3) + 8 * (r >> 2) + 4 * h5;
                slds[wid * 64 + row] = sc2[m][r];
            }
    }
    __syncthreads();
    if (t < 64) {
        float v = 0.f;
#pragma unroll
        for (int w = 0; w < 8; ++w) v += slds[w * 64 + t];
        scores_part[(size_t)hhalf * SPART + m_base + t] = v;
    }
}

// ---- kernel 3: row softmax over S=2048 per batch (sums the two h-half partials) ----
__global__ void softmax_k(const float* __restrict__ sc, float* __restrict__ out) {
    const int b = blockIdx.x;   // 32
    const int t = threadIdx.x;  // 256
    const int lane = t & 63;
    const int w = t >> 6;
    const float* r0 = sc + (size_t)b * 2048;
    const float* r1 = sc + SPART + (size_t)b * 2048;
    float x[8];
#pragma unroll
    for (int i = 0; i < 8; ++i) x[i] = r0[i * 256 + t] + r1[i * 256 + t];
    float m = x[0];
#pragma unroll
    for (int i = 1; i < 8; ++i) m = fmaxf(m, x[i]);
#pragma unroll
    for (int off = 32; off >= 1; off >>= 1) m = fmaxf(m, __shfl_xor(m, off, 64));
    __shared__ float sred[4];
    __shared__ float sred2[4];
    if (lane == 0) sred[w] = m;
    __syncthreads();
    m = fmaxf(fmaxf(sred[0], sred[1]), fmaxf(sred[2], sred[3]));
    float ssum = 0.f;
#pragma unroll
    for (int i = 0; i < 8; ++i) { x[i] = expf(x[i] - m); ssum += x[i]; }
#pragma unroll
    for (int off = 32; off >= 1; off >>= 1) ssum += __shfl_xor(ssum, off, 64);
    if (lane == 0) sred2[w] = ssum;
    __syncthreads();
    const float inv = 1.0f / (sred2[0] + sred2[1] + sred2[2] + sred2[3]);
#pragma unroll
    for (int i = 0; i < 8; ++i) out[(size_t)b * 2048 + i * 256 + t] = x[i] * inv;
}

extern "C" void kernel_launch(void* const* d_in, const int* in_sizes, int n_in,
                              void* d_out, int out_size, void* d_ws, size_t ws_size,
                              hipStream_t stream) {
    const float* s      = (const float*)d_in[0];
    const float* enc    = (const float*)d_in[1];
    const float* attn_w = (const float*)d_in[2];
    const float* vw     = (const float*)d_in[3];
    float* out = (float*)d_out;

    unsigned short* we = (unsigned short*)d_ws;                             // 2 MB bf16 we_t
    float* ps     = (float*)((char*)d_ws + (2u << 20));                     // 128 KB proj_s
    float* scores = (float*)((char*)d_ws + (2u << 20) + (128u << 10));      // 512 KB partials

    cvt_we_k<<<1024, 256, 0, stream>>>(attn_w, we);
    proj_s_k<<<256, 256, 0, stream>>>(s, attn_w, ps);
    fused_main_k<<<2048, 512, 0, stream>>>(enc, we, ps, vw, scores);
    softmax_k<<<32, 256, 0, stream>>>(scores, out);
}

// Round 6
// 217.211 us; speedup vs baseline: 1.3454x; 1.3454x over previous
//
#include <hip/hip_runtime.h>
#include <hip/hip_bf16.h>

#define KDIM 1024   // 2*ENC_H
#define HDIM 1024   // DEC_H
#define BM   64
#define SPART 65536

typedef __attribute__((ext_vector_type(8))) short bf16x8_t;
typedef __attribute__((ext_vector_type(16))) float f32x16_t;
typedef __attribute__((ext_vector_type(4))) float f32x4_t;
typedef __attribute__((ext_vector_type(4))) unsigned int u32x4_t;
typedef __attribute__((ext_vector_type(2))) unsigned int u32x2_t;

__device__ __forceinline__ unsigned int pack2bf(float a, float b) {
    union { float f; unsigned int u; } ua, ub;
    ua.f = a; ub.f = b;
    unsigned int ra = (ua.u + 0x7fffu + ((ua.u >> 16) & 1u)) >> 16;  // RNE
    unsigned int rb = (ub.u + 0x7fffu + ((ub.u >> 16) & 1u)) >> 16;
    return ra | (rb << 16);
}

__device__ __forceinline__ unsigned int cvtpk(float lo, float hi) {
    unsigned int r;
    asm("v_cvt_pk_bf16_f32 %0, %1, %2" : "=v"(r) : "v"(lo), "v"(hi));
    return r;
}

// ---- kernel 1a: W_e -> bf16, fragment-order layout we_t[ks][h][16] ----
// element (h, e) -> we_t[(e>>4)*16384 + h*16 + (e&15)]
__global__ void cvt_we_k(const float* __restrict__ attn_w, unsigned short* __restrict__ we_t) {
    const int h = blockIdx.x;      // 1024
    const int t = threadIdx.x;     // 256 (handles e = 4t..4t+3)
    const f32x4_t v = *(const f32x4_t*)(attn_w + (size_t)h * 2048 + 1024 + (size_t)t * 4);
    u32x2_t o;
    o[0] = pack2bf(v[0], v[1]);
    o[1] = pack2bf(v[2], v[3]);
    const int ks  = t >> 2;         // e/16
    const int e15 = (t & 3) * 4;    // e&15
    *(u32x2_t*)&we_t[(size_t)ks * 16384 + h * 16 + e15] = o;
}

// ---- kernel 1b: proj_s[b][h] = sum_d s[b,d] * attn_w[h, d]  (fp32) ----
__global__ void proj_s_k(const float* __restrict__ s, const float* __restrict__ attn_w,
                         float* __restrict__ ps) {
    const int h = (blockIdx.x * blockDim.x + threadIdx.x) >> 6;  // 0..1023
    const int lane = threadIdx.x & 63;
    const float* wr = attn_w + (size_t)h * 2048;
    float w[16];
#pragma unroll
    for (int i = 0; i < 16; ++i) w[i] = wr[lane + 64 * i];
    for (int b = 0; b < 32; ++b) {
        const float* sr = s + (size_t)b * 1024;
        float a = 0.f;
#pragma unroll
        for (int i = 0; i < 16; ++i) a = fmaf(w[i], sr[lane + 64 * i], a);
#pragma unroll
        for (int off = 32; off >= 1; off >>= 1) a += __shfl_xor(a, off, 64);
        if (lane == 0) ps[b * 1024 + h] = a;
    }
}

// ---- kernel 2: fused pe-GEMM(32x32x16 MFMA) + tanh + v-dot -> partial scores ----
// R4 structure + counted-wait barrier (lgkmcnt(0) + raw s_barrier, NO sched fences):
// global prefetches ride across kc boundaries; regalloc keeps full freedom (no spill).
__launch_bounds__(512, 4)
__global__ void fused_main_k(const float* __restrict__ enc,
                             const unsigned short* __restrict__ we_t,
                             const float* __restrict__ ps,
                             const float* __restrict__ vw,
                             float* __restrict__ scores_part) {
    __shared__ unsigned short lds_a[2 * 64 * 128];  // 32 KB ring

    const int t = threadIdx.x;
    const int bid = blockIdx.x;
    const int hhalf = bid & 1;                      // siblings adjacent -> L3/L2 reuse
    const int rest = bid >> 1;                      // 0..1023
    const int m_swz = (rest & 7) * 128 + (rest >> 3);   // XCD-bijective
    const int m_base = m_swz * BM;
    const int bidx = m_swz >> 5;        // batch index

    const int lane = t & 63;
    const int wid  = t >> 6;        // 0..7
    const int l31  = lane & 31;
    const int h5   = lane >> 5;     // 0..1
    const int habs = hhalf * 512 + wid * 64;

    // staging geometry: thread covers rows {srow, 32+srow}, 16B chunk sc8
    const int srow = t >> 4;        // 0..31
    const int sc8  = t & 15;

    auto stage_load_half = [&](int kc, int half, f32x4_t* r) {
        const int row = half * 32 + srow;
        const float* p = enc + (size_t)(m_base + row) * KDIM + kc * 128 + sc8 * 8;
        r[0] = *(const f32x4_t*)p;
        r[1] = *(const f32x4_t*)(p + 4);
    };
    auto stage_write_half = [&](int kc, int half, const f32x4_t* r) {
        const int slot = kc & 1;
        const int row = half * 32 + srow;
        u32x4_t pk;
        pk[0] = cvtpk(r[0][0], r[0][1]);
        pk[1] = cvtpk(r[0][2], r[0][3]);
        pk[2] = cvtpk(r[1][0], r[1][1]);
        pk[3] = cvtpk(r[1][2], r[1][3]);
        *(u32x4_t*)&lds_a[slot * 8192 + row * 128 + ((sc8 ^ (row & 15)) << 3)] = pk;
    };

    // B: fragment-order; frag(g, nf) at btile + g*16384 + nf*512 (shorts)
    const unsigned short* btile = we_t + (size_t)(habs + l31) * 16 + h5 * 8;
    auto loadB = [&](int g, bf16x8_t* dst) {
        const unsigned short* bp = btile + (size_t)g * 16384;
        dst[0] = *(const bf16x8_t*)(bp);
        dst[1] = *(const bf16x8_t*)(bp + 512);
    };

    f32x16_t acc[2][2];
#pragma unroll
    for (int m = 0; m < 2; ++m)
#pragma unroll
        for (int nf = 0; nf < 2; ++nf)
#pragma unroll
            for (int r = 0; r < 16; ++r) acc[m][nf][r] = 0.f;

    bf16x8_t bbuf[4][2];
    f32x4_t rsA[2], rsB[2];

    // prologue: B prefetch g=0..2, stage kc=0 into slot 0
    loadB(0, bbuf[0]);
    loadB(1, bbuf[1]);
    loadB(2, bbuf[2]);
    stage_load_half(0, 0, rsA);
    stage_load_half(0, 1, rsB);
    stage_write_half(0, 0, rsA);
    stage_write_half(0, 1, rsB);
    __syncthreads();

#pragma unroll
    for (int g = 0; g < 64; ++g) {
        const int kc  = g >> 3;
        const int ksl = g & 7;

        if (g + 3 < 64) loadB(g + 3, bbuf[(g + 3) & 3]);          // depth-3 B prefetch
        if (ksl == 0 && kc < 7) stage_load_half(kc + 1, 0, rsA);  // ~3 g cover
        if (ksl == 4 && kc < 7) stage_load_half(kc + 1, 1, rsB);

        const unsigned short* slotp = lds_a + (kc & 1) * 8192;
        const int ch = (((ksl << 1) + h5) ^ (l31 & 15)) << 3;     // 4-bit row-XOR swizzle
        const bf16x8_t a0 = *(const bf16x8_t*)&slotp[l31 * 128 + ch];
        const bf16x8_t a1 = *(const bf16x8_t*)&slotp[(32 + l31) * 128 + ch];
        const bf16x8_t* bfr = bbuf[g & 3];
        __builtin_amdgcn_s_setprio(1);
        acc[0][0] = __builtin_amdgcn_mfma_f32_32x32x16_bf16(a0, bfr[0], acc[0][0], 0, 0, 0);
        acc[1][0] = __builtin_amdgcn_mfma_f32_32x32x16_bf16(a1, bfr[0], acc[1][0], 0, 0, 0);
        acc[0][1] = __builtin_amdgcn_mfma_f32_32x32x16_bf16(a0, bfr[1], acc[0][1], 0, 0, 0);
        acc[1][1] = __builtin_amdgcn_mfma_f32_32x32x16_bf16(a1, bfr[1], acc[1][1], 0, 0, 0);
        __builtin_amdgcn_s_setprio(0);

        if (ksl == 3 && kc < 7) stage_write_half(kc + 1, 0, rsA);
        if (ksl == 7) {
            if (kc < 7) stage_write_half(kc + 1, 1, rsB);
            // counted-wait barrier: drain LDS ops only; global prefetches stay in flight
            asm volatile("s_waitcnt lgkmcnt(0)" ::: "memory");
            __builtin_amdgcn_s_barrier();
        }
    }

    // ---- epilogue: tanh(ps + pe) * v, per-lane partials over C-rows ----
    float sc2[2][16];
#pragma unroll
    for (int m = 0; m < 2; ++m)
#pragma unroll
        for (int r = 0; r < 16; ++r) sc2[m][r] = 0.f;

#pragma unroll
    for (int nf = 0; nf < 2; ++nf) {
        const int h = habs + nf * 32 + l31;
        const float pv = ps[bidx * 1024 + h];
        const float vv = vw[h];
#pragma unroll
        for (int m = 0; m < 2; ++m)
#pragma unroll
            for (int r = 0; r < 16; ++r) {
                const float x = acc[m][nf][r] + pv;
                const float e = __expf(2.0f * x);
                const float th = 1.0f - __fdividef(2.0f, e + 1.0f);
                sc2[m][r] = fmaf(vv, th, sc2[m][r]);
            }
    }

    // reduce over the 32-lane column group (h dimension); h5 preserved
#pragma unroll
    for (int off = 1; off < 32; off <<= 1)
#pragma unroll
        for (int m = 0; m < 2; ++m)
#pragma unroll
            for (int r = 0; r < 16; ++r)
                sc2[m][r] += __shfl_xor(sc2[m][r], off, 64);

    __syncthreads();   // loop done; safe to reuse LDS front as partials buffer
    float* slds = (float*)lds_a;   // [8 waves][64 rows]
    if (l31 == 0) {
#pragma unroll
        for (int m = 0; m < 2; ++m)
#pragma unroll
            for (int r = 0; r < 16; ++r) {
                const int row = m * 32 + (r & 3) + 8 * (r >> 2) + 4 * h5;
                slds[wid * 64 + row] = sc2[m][r];
            }
    }
    __syncthreads();
    if (t < 64) {
        float v = 0.f;
#pragma unroll
        for (int w = 0; w < 8; ++w) v += slds[w * 64 + t];
        scores_part[(size_t)hhalf * SPART + m_base + t] = v;
    }
}

// ---- kernel 3: row softmax over S=2048 per batch (sums the two h-half partials) ----
__global__ void softmax_k(const float* __restrict__ sc, float* __restrict__ out) {
    const int b = blockIdx.x;   // 32
    const int t = threadIdx.x;  // 256
    const int lane = t & 63;
    const int w = t >> 6;
    const float* r0 = sc + (size_t)b * 2048;
    const float* r1 = sc + SPART + (size_t)b * 2048;
    float x[8];
#pragma unroll
    for (int i = 0; i < 8; ++i) x[i] = r0[i * 256 + t] + r1[i * 256 + t];
    float m = x[0];
#pragma unroll
    for (int i = 1; i < 8; ++i) m = fmaxf(m, x[i]);
#pragma unroll
    for (int off = 32; off >= 1; off >>= 1) m = fmaxf(m, __shfl_xor(m, off, 64));
    __shared__ float sred[4];
    __shared__ float sred2[4];
    if (lane == 0) sred[w] = m;
    __syncthreads();
    m = fmaxf(fmaxf(sred[0], sred[1]), fmaxf(sred[2], sred[3]));
    float ssum = 0.f;
#pragma unroll
    for (int i = 0; i < 8; ++i) { x[i] = expf(x[i] - m); ssum += x[i]; }
#pragma unroll
    for (int off = 32; off >= 1; off >>= 1) ssum += __shfl_xor(ssum, off, 64);
    if (lane == 0) sred2[w] = ssum;
    __syncthreads();
    const float inv = 1.0f / (sred2[0] + sred2[1] + sred2[2] + sred2[3]);
#pragma unroll
    for (int i = 0; i < 8; ++i) out[(size_t)b * 2048 + i * 256 + t] = x[i] * inv;
}

extern "C" void kernel_launch(void* const* d_in, const int* in_sizes, int n_in,
                              void* d_out, int out_size, void* d_ws, size_t ws_size,
                              hipStream_t stream) {
    const float* s      = (const float*)d_in[0];
    const float* enc    = (const float*)d_in[1];
    const float* attn_w = (const float*)d_in[2];
    const float* vw     = (const float*)d_in[3];
    float* out = (float*)d_out;

    unsigned short* we = (unsigned short*)d_ws;                             // 2 MB bf16 we_t
    float* ps     = (float*)((char*)d_ws + (2u << 20));                     // 128 KB proj_s
    float* scores = (float*)((char*)d_ws + (2u << 20) + (128u << 10));      // 512 KB partials

    cvt_we_k<<<1024, 256, 0, stream>>>(attn_w, we);
    proj_s_k<<<256, 256, 0, stream>>>(s, attn_w, ps);
    fused_main_k<<<2048, 512, 0, stream>>>(enc, we, ps, vw, scores);
    softmax_k<<<32, 256, 0, stream>>>(scores, out);
}